// Round 6
// baseline (4904.298 us; speedup 1.0000x reference)
//
#include <hip/hip_runtime.h>
#include <hip/hip_bf16.h>
#include <math.h>

#define B    128
#define CIN  256
#define HIN  8
#define WIN_ 32
#define RH   16
#define RW   64
#define HID  256
#define NC   163
#define T    32
#define L    256
#define CENC 296
#define RINW 832   // [0..255 emb][256..551 ctx][552..575 zero pad][576..831 h]

typedef __attribute__((ext_vector_type(8))) short short8;
typedef __attribute__((ext_vector_type(8))) unsigned short u16x8;
typedef __attribute__((ext_vector_type(4))) float f32x4;

__device__ __forceinline__ float bf2f(unsigned short u) {
    unsigned int x = ((unsigned int)u) << 16;
    return __uint_as_float(x);
}
__device__ __forceinline__ unsigned short f2bf(float f) {
    unsigned int x = __float_as_uint(f);
    unsigned int r = (x + 0x7FFFu + ((x >> 16) & 1u)) >> 16;
    return (unsigned short)r;
}
__device__ __forceinline__ float fast_tanh(float x) {
    float e = __expf(2.f * x);
    return 1.f - 2.f * __builtin_amdgcn_rcpf(e + 1.f);
}
__device__ __forceinline__ float fast_sigm(float x) {
    return __builtin_amdgcn_rcpf(1.f + __expf(-x));
}
__device__ __forceinline__ float wave_red_max(float v) {
    #pragma unroll
    for (int o = 32; o > 0; o >>= 1) v = fmaxf(v, __shfl_down(v, o, 64));
    return v;
}
__device__ __forceinline__ float wave_red_sum(float v) {
    #pragma unroll
    for (int o = 32; o > 0; o >>= 1) v += __shfl_down(v, o, 64);
    return v;
}
__device__ __forceinline__ float half_red_sum(float v) {
    #pragma unroll
    for (int o = 16; o > 0; o >>= 1) v += __shfl_down(v, o, 64);
    return v;
}

// ---------------- bilinear upsample fused with transpose → Xt[b][y][x][ci] bf16 ----------------
__global__ void __launch_bounds__(256) k_upsxt(const float* __restrict__ x,
                                               unsigned short* __restrict__ Xt) {
    __shared__ __align__(16) float sf[64 * 2 * 32];
    const int y = blockIdx.x;
    const int b = blockIdx.y;
    const int tid = threadIdx.x;
    float sy = 0.5f * y - 0.25f;
    int yq0 = (y - 1) >> 1;
    float wy = sy - (float)yq0;
    int y0c = min(max(yq0, 0), HIN - 1);
    int y1c = min(max(yq0 + 1, 0), HIN - 1);
    const int xo = tid & 63;
    const int cj = tid >> 6;
    float sx = 0.5f * xo - 0.25f;
    int xq0 = (xo - 1) >> 1;
    float wx = sx - (float)xq0;
    int x0c = min(max(xq0, 0), WIN_ - 1);
    int x1c = min(max(xq0 + 1, 0), WIN_ - 1);
    for (int cc = 0; cc < 4; cc++) {
        __syncthreads();
        #pragma unroll
        for (int i = 0; i < 4; i++) {
            int idx = tid * 4 + i;
            int c = idx >> 4;
            int rowh = (idx >> 3) & 1;
            int part = idx & 7;
            int ysrc = rowh ? y1c : y0c;
            float4 v = *reinterpret_cast<const float4*>(
                x + ((size_t)(b * CIN + cc * 64 + c) * HIN + ysrc) * WIN_ + part * 4);
            *reinterpret_cast<float4*>(sf + ((c * 2 + rowh) * 32 + part * 4)) = v;
        }
        __syncthreads();
        unsigned short ov[16];
        #pragma unroll
        for (int j = 0; j < 16; j++) {
            int c = cj * 16 + j;
            const float* r0 = sf + (c * 2 + 0) * 32;
            const float* r1 = sf + (c * 2 + 1) * 32;
            float v = (1.f - wy) * ((1.f - wx) * r0[x0c] + wx * r0[x1c])
                    +        wy  * ((1.f - wx) * r1[x0c] + wx * r1[x1c]);
            ov[j] = f2bf(v);
        }
        unsigned short* dst = Xt + ((size_t)((b * 16 + y) * 64 + xo)) * 256 + cc * 64 + cj * 16;
        *reinterpret_cast<u16x8*>(dst)     = *reinterpret_cast<u16x8*>(ov);
        *reinterpret_cast<u16x8*>(dst + 8) = *reinterpret_cast<u16x8*>(ov + 8);
    }
}

// ---------------- weight transform: Wt[s][co][ci] bf16 ----------------
__global__ void k_wt(const float* __restrict__ conv_w, unsigned short* __restrict__ Wt) {
    int e = blockIdx.x * 256 + threadIdx.x;
    int ci = e & 255;
    int co = (e >> 8) & 255;
    int s  = e >> 16;
    Wt[(size_t)(s * 256 + co) * 256 + ci] = f2bf(conv_w[(size_t)(co * 256 + ci) * 9 + s]);
}

// ---------------- conv3x3 MFMA implicit GEMM + fused bias/ReLU/pool → enc_bf ----------------
__global__ void __launch_bounds__(256) k_convmm(const unsigned short* __restrict__ Xt,
        const unsigned short* __restrict__ Wt, const float* __restrict__ conv_b,
        unsigned short* __restrict__ enc_bf) {
    __shared__ __align__(16) char smem[34048];
    unsigned short* A_s = (unsigned short*)smem;
    unsigned short* B_s = A_s + 128 * 40;
    float* pool = (float*)smem;
    const int mt = blockIdx.x;
    const int n0 = blockIdx.y * 128;
    const int b = mt >> 3;
    const int y0 = (mt & 7) * 2;
    const int tid = threadIdx.x;
    const int wave = tid >> 6, lane = tid & 63;
    const int mq = (wave & 1) * 64, nq = (wave >> 1) * 64;
    const int lm = lane & 15, lq = lane >> 4;
    f32x4 acc[4][4];
    #pragma unroll
    for (int mi = 0; mi < 4; mi++)
        #pragma unroll
        for (int ni = 0; ni < 4; ni++)
            #pragma unroll
            for (int r = 0; r < 4; r++) acc[mi][ni][r] = 0.f;

    for (int s9 = 0; s9 < 9; s9++) {
        const int ky = s9 / 3, kx = s9 % 3;
        const unsigned short* Wb = Wt + (size_t)s9 * 256 * 256;
        for (int kc = 0; kc < 256; kc += 32) {
            __syncthreads();
            #pragma unroll
            for (int it = 0; it < 2; it++) {
                int s2 = tid + it * 256;
                int pix = s2 >> 2, q4 = s2 & 3;
                int yy = y0 + (pix >> 6) + ky - 1;
                int xx = (pix & 63) + kx - 1;
                u16x8 va = {0, 0, 0, 0, 0, 0, 0, 0};
                if ((unsigned)yy < 16u && (unsigned)xx < 64u)
                    va = *reinterpret_cast<const u16x8*>(
                        Xt + ((size_t)((b * 16 + yy) * 64 + xx)) * 256 + kc + q4 * 8);
                *reinterpret_cast<u16x8*>(A_s + pix * 40 + q4 * 8) = va;
                u16x8 vb = *reinterpret_cast<const u16x8*>(
                    Wb + (size_t)(n0 + pix) * 256 + kc + q4 * 8);
                *reinterpret_cast<u16x8*>(B_s + pix * 40 + q4 * 8) = vb;
            }
            __syncthreads();
            short8 af[4], bfr[4];
            #pragma unroll
            for (int mi = 0; mi < 4; mi++)
                af[mi] = *reinterpret_cast<const short8*>(A_s + (mq + mi * 16 + lm) * 40 + lq * 8);
            #pragma unroll
            for (int ni = 0; ni < 4; ni++)
                bfr[ni] = *reinterpret_cast<const short8*>(B_s + (nq + ni * 16 + lm) * 40 + lq * 8);
            #pragma unroll
            for (int mi = 0; mi < 4; mi++)
                #pragma unroll
                for (int ni = 0; ni < 4; ni++)
                    acc[mi][ni] = __builtin_amdgcn_mfma_f32_16x16x32_bf16(
                        af[mi], bfr[ni], acc[mi][ni], 0, 0, 0);
        }
    }
    __syncthreads();
    #pragma unroll
    for (int mi = 0; mi < 4; mi++) {
        int px0 = mi * 8 + lq * 2;
        #pragma unroll
        for (int ni = 0; ni < 4; ni++) {
            int nl = nq + ni * 16 + lm;
            float pa = fmaxf(acc[mi][ni][0], acc[mi][ni][1]);
            float pb = fmaxf(acc[mi][ni][2], acc[mi][ni][3]);
            pool[((wave & 1) * 32 + px0) * 132 + nl] = pa;
            pool[((wave & 1) * 32 + px0 + 1) * 132 + nl] = pb;
        }
    }
    __syncthreads();
    {
        int base = tid * 16;
        int px = base >> 7;
        int nb = base & 127;
        unsigned short ov[16];
        #pragma unroll
        for (int i = 0; i < 16; i++) {
            int n = nb + i;
            float v = fmaxf(pool[px * 132 + n], pool[(32 + px) * 132 + n]) + conv_b[n0 + n];
            ov[i] = f2bf(fmaxf(v, 0.f));
        }
        unsigned short* dst = enc_bf + ((size_t)b * L + (mt & 7) * 32 + px) * CENC + n0 + nb;
        *reinterpret_cast<u16x8*>(dst)     = *reinterpret_cast<u16x8*>(ov);
        *reinterpret_cast<u16x8*>(dst + 8) = *reinterpret_cast<u16x8*>(ov + 8);
    }
}

// ---------------- positional channels (bf16) + pos2t[40][256] bf16 ----------------
__global__ void k_encpos(const float* __restrict__ x_emb, const float* __restrict__ y_emb,
                         unsigned short* __restrict__ enc_bf, unsigned short* __restrict__ pos2t) {
    int b = blockIdx.x, l = threadIdx.x;
    int yl = l >> 5, xl = l & 31;
    unsigned short* e = enc_bf + (size_t)(b * L + l) * CENC + 256;
    #pragma unroll
    for (int c = 0; c < 32; c++) e[c] = f2bf(x_emb[xl * 32 + c]);
    #pragma unroll
    for (int c = 0; c < 8; c++) e[32 + c] = f2bf(y_emb[yl * 8 + c]);
    if (b == 0) {
        #pragma unroll
        for (int c = 0; c < 32; c++) pos2t[c * 256 + l] = f2bf(x_emb[xl * 32 + c]);
        #pragma unroll
        for (int c = 0; c < 8; c++) pos2t[(32 + c) * 256 + l] = f2bf(y_emb[yl * 8 + c]);
    }
}

// ---------------- enc_t[b][c][l] bf16 ----------------
__global__ void __launch_bounds__(256) k_enct(const unsigned short* __restrict__ enc_bf,
                                              unsigned short* __restrict__ enc_t) {
    __shared__ unsigned short s[64 * 264];
    const int c0 = blockIdx.x * 64;
    const int b = blockIdx.y;
    const int tid = threadIdx.x;
    #pragma unroll
    for (int j = 0; j < 8; j++) {
        u16x8 u = *reinterpret_cast<const u16x8*>(
            enc_bf + ((size_t)b * L + tid) * CENC + c0 + j * 8);
        #pragma unroll
        for (int k = 0; k < 8; k++) s[(j * 8 + k) * 264 + tid] = u[k];
    }
    __syncthreads();
    {
        int c = tid >> 2, lp = tid & 3;
        const unsigned short* row = s + c * 264 + lp * 64;
        unsigned short* dst = enc_t + ((size_t)b * 256 + c0 + c) * L + lp * 64;
        #pragma unroll
        for (int i = 0; i < 8; i++)
            *reinterpret_cast<u16x8*>(dst + i * 8) =
                *reinterpret_cast<const u16x8*>(row + i * 8);
    }
}

// ---------------- E_bf[v][h] bf16 ----------------
__global__ void __launch_bounds__(256) k_etab(const float* __restrict__ emb_dec,
                                              const float* __restrict__ word_w,
                                              const float* __restrict__ word_b,
                                              unsigned short* __restrict__ E_bf) {
    __shared__ float er[NC];
    int row = blockIdx.x, tid = threadIdx.x;
    for (int k = tid; k < NC; k += 256) er[k] = emb_dec[(size_t)row * NC + k];
    __syncthreads();
    float a = word_b[tid];
    for (int k = 0; k < NC; k++) a += er[k] * word_w[(size_t)tid * NC + k];
    E_bf[(size_t)row * HID + tid] = f2bf(a);
}

// ---------------- row-major bf16 weight casts ----------------
__global__ void k_prep(const float* __restrict__ attn_w, const float* __restrict__ out_w,
                       unsigned short* __restrict__ wA_bf, unsigned short* __restrict__ ow_bf) {
    int o = blockIdx.x, k = threadIdx.x;
    wA_bf[(size_t)o * 256 + k] = f2bf(attn_w[(size_t)o * 552 + k]);
    if (o < NC) ow_bf[(size_t)o * 256 + k] = f2bf(out_w[(size_t)o * 256 + k]);
}

// ---------------- transposed GRU weights: WgT1[576][768], WgT2[256][768] bf16 ----------------
// WgT1[k][g] = wih[g][k] (k<552, else 0); WgT2[k][g] = whh[g][k]
__global__ void __launch_bounds__(768) k_wg(const float* __restrict__ wih,
                                            const float* __restrict__ whh,
                                            unsigned short* __restrict__ WgT1,
                                            unsigned short* __restrict__ WgT2) {
    int k = blockIdx.x, g = threadIdx.x;
    if (k < 576) {
        WgT1[(size_t)k * 768 + g] = (k < 552) ? f2bf(wih[(size_t)g * 552 + k]) : 0;
    } else {
        int k2 = k - 576;
        WgT2[(size_t)k2 * 768 + g] = f2bf(whh[(size_t)g * 256 + k2]);
    }
}

// ---------------- ep_t[b][l][h] bf16 ----------------
__global__ void __launch_bounds__(256) k_ep(const unsigned short* __restrict__ enc_bf,
                                            const float* __restrict__ attn_w,
                                            unsigned short* __restrict__ ep_t) {
    __shared__ __align__(16) float eS[16][132];
    __shared__ __align__(16) float wS[16][36];
    const int l0 = blockIdx.x * 128;
    const int h0 = blockIdx.y * 32;
    const int b = blockIdx.z;
    const int tid = threadIdx.x;
    const int hh = tid >> 5, ll = tid & 31;
    float acc[4][4];
    #pragma unroll
    for (int s2 = 0; s2 < 4; s2++)
        #pragma unroll
        for (int r = 0; r < 4; r++) acc[s2][r] = 0.f;
    for (int kc = 0; kc < CENC; kc += 16) {
        const int kn = min(16, CENC - kc);
        __syncthreads();
        #pragma unroll
        for (int it = 0; it < 2; it++) {
            int idx = it * 256 + tid;
            int lq = idx >> 2, kq = idx & 3;
            float v0 = 0.f, v1 = 0.f, v2 = 0.f, v3 = 0.f;
            if (kq * 4 < kn) {
                ushort4 u = *reinterpret_cast<const ushort4*>(
                    enc_bf + (size_t)(b * L + l0 + lq) * CENC + kc + kq * 4);
                v0 = bf2f(u.x); v1 = bf2f(u.y); v2 = bf2f(u.z); v3 = bf2f(u.w);
            }
            eS[kq * 4 + 0][lq] = v0; eS[kq * 4 + 1][lq] = v1;
            eS[kq * 4 + 2][lq] = v2; eS[kq * 4 + 3][lq] = v3;
        }
        if (tid < 128) {
            int hq = tid >> 2, kq = tid & 3;
            float4 v = make_float4(0.f, 0.f, 0.f, 0.f);
            if (kq * 4 < kn)
                v = *reinterpret_cast<const float4*>(attn_w + (size_t)(h0 + hq) * 552 + 256 + kc + kq * 4);
            wS[kq * 4 + 0][hq] = v.x; wS[kq * 4 + 1][hq] = v.y;
            wS[kq * 4 + 2][hq] = v.z; wS[kq * 4 + 3][hq] = v.w;
        }
        __syncthreads();
        #pragma unroll
        for (int k = 0; k < 16; k++) {
            float4 e = *reinterpret_cast<const float4*>(&eS[k][ll * 4]);
            float4 w = *reinterpret_cast<const float4*>(&wS[k][hh * 4]);
            float ev[4] = {e.x, e.y, e.z, e.w};
            float wv[4] = {w.x, w.y, w.z, w.w};
            #pragma unroll
            for (int s2 = 0; s2 < 4; s2++)
                #pragma unroll
                for (int r = 0; r < 4; r++) acc[s2][r] += wv[s2] * ev[r];
        }
    }
    #pragma unroll
    for (int r = 0; r < 4; r++) {
        ushort4 o;
        o.x = f2bf(acc[0][r]); o.y = f2bf(acc[1][r]);
        o.z = f2bf(acc[2][r]); o.w = f2bf(acc[3][r]);
        *reinterpret_cast<ushort4*>(
            ep_t + ((size_t)(b * L) + l0 + ll * 4 + r) * HID + h0 + hh * 4) = o;
    }
}

// ---------------- persistent per-b recurrence: NO inter-block sync ----------------
// 128 blocks × 1024 threads; block b owns batch element b for all T steps.
// Gates via per-b GEMV with transposed weights (coalesced over g), K-split by wave.
__global__ void __launch_bounds__(1024) k_loop(
        const unsigned short* __restrict__ ep_t, const unsigned short* __restrict__ enc_t,
        const unsigned short* __restrict__ wA_bf, const unsigned short* __restrict__ ow_bf,
        const unsigned short* __restrict__ E_bf, const unsigned short* __restrict__ pos2t,
        const unsigned short* __restrict__ WgT1, const unsigned short* __restrict__ WgT2,
        const float* __restrict__ attn_b, const float* __restrict__ attn_v,
        const float* __restrict__ out_b, const float* __restrict__ bih,
        const float* __restrict__ bhh, const int* __restrict__ dec_tgt,
        const int* __restrict__ word_tgt, float* __restrict__ nllG) {
    const int b = blockIdx.x;
    const int tid = threadIdx.x;
    const int hwid = tid >> 5, l32 = tid & 31;
    const int wave = tid >> 6, lane = tid & 63;

    __shared__ float parts[16][768];          // 48KB GEMV partials
    __shared__ float gi_s[768], gh_s[768];    // 6KB
    __shared__ unsigned short rin_s[RINW];    // 1.7KB
    __shared__ float hS_f[256];
    __shared__ unsigned short hS_bf[256], hp_bf[256], v_bf[256], s_bf[256];
    __shared__ float scr[256];
    __shared__ float red[16];
    __shared__ float nllA[1];

    if (tid < 256) v_bf[tid] = f2bf(attn_v[tid]);
    if (tid >= 552 && tid < 576) rin_s[tid] = 0;   // K-pad
    if (tid == 0) nllA[0] = 0.f;

    for (int t = 0; t <= T; t++) {
        __syncthreads();
        // ---- s0: GRU pointwise: h_t from gates of step t-1 (LDS gi_s/gh_s) ----
        if (tid < 256) {
            float h;
            if (t == 0) {
                h = 0.f;
            } else {
                float hold = hS_f[tid];
                float r_ = fast_sigm(gi_s[tid] + bih[tid] + gh_s[tid] + bhh[tid]);
                float z_ = fast_sigm(gi_s[256 + tid] + bih[256 + tid] + gh_s[256 + tid] + bhh[256 + tid]);
                float n_ = fast_tanh(gi_s[512 + tid] + bih[512 + tid] + r_ * (gh_s[512 + tid] + bhh[512 + tid]));
                h = (1.f - z_) * n_ + z_ * hold;
            }
            hS_f[tid] = h;
            unsigned short hb = f2bf(h);
            hS_bf[tid] = hb;
            rin_s[576 + tid] = hb;
        }
        __syncthreads();

        // ---- s1 (t>0): logits(h_t) + nll vs word_targets[t-1] ----
        if (t > 0) {
            #pragma unroll
            for (int it = 0; it < 6; it++) {
                int row = it * 32 + hwid;
                float d = 0.f;
                if (row < NC) {
                    u16x8 w = *reinterpret_cast<const u16x8*>(ow_bf + (size_t)row * 256 + l32 * 8);
                    u16x8 hh = *reinterpret_cast<const u16x8*>(hS_bf + l32 * 8);
                    #pragma unroll
                    for (int j = 0; j < 8; j++) d += bf2f(w[j]) * bf2f(hh[j]);
                }
                d = half_red_sum(d);
                if (l32 == 0 && row < NC) scr[row] = d + out_b[row];
            }
            __syncthreads();
            float lg = -1e30f;
            if (tid < 256) {
                if (tid < NC) lg = scr[tid];
                float m = wave_red_max(lg);
                if ((tid & 63) == 0) red[tid >> 6] = m;
            }
            __syncthreads();
            float M = fmaxf(fmaxf(red[0], red[1]), fmaxf(red[2], red[3]));
            if (tid < 256) {
                float e = (tid < NC) ? __expf(lg - M) : 0.f;
                float sm = wave_red_sum(e);
                if ((tid & 63) == 0) red[8 + (tid >> 6)] = sm;
            }
            __syncthreads();
            if (tid == 0) {
                float S = red[8] + red[9] + red[10] + red[11];
                int tgt = word_tgt[b * T + (t - 1)];
                if (tgt >= 0) nllA[0] += M + __logf(S) - scr[tgt];
            }
        }
        if (t == T) break;
        __syncthreads();

        // ---- s2: hp = h @ Wh^T + attn_b ----
        #pragma unroll
        for (int it = 0; it < 8; it++) {
            int row = it * 32 + hwid;
            u16x8 w = *reinterpret_cast<const u16x8*>(wA_bf + (size_t)row * 256 + l32 * 8);
            u16x8 hh = *reinterpret_cast<const u16x8*>(hS_bf + l32 * 8);
            float d = 0.f;
            #pragma unroll
            for (int j = 0; j < 8; j++) d += bf2f(w[j]) * bf2f(hh[j]);
            d = half_red_sum(d);
            if (l32 == 0) hp_bf[row] = f2bf(d + attn_b[row]);
        }
        __syncthreads();

        // ---- s3: scores over l ----
        #pragma unroll
        for (int it = 0; it < 8; it++) {
            int row = it * 32 + hwid;
            u16x8 e = *reinterpret_cast<const u16x8*>(ep_t + ((size_t)b * L + row) * 256 + l32 * 8);
            u16x8 hp = *reinterpret_cast<const u16x8*>(hp_bf + l32 * 8);
            u16x8 vv = *reinterpret_cast<const u16x8*>(v_bf + l32 * 8);
            float d = 0.f;
            #pragma unroll
            for (int j = 0; j < 8; j++)
                d += bf2f(vv[j]) * fast_tanh(bf2f(e[j]) + bf2f(hp[j]));
            d = half_red_sum(d);
            if (l32 == 0) scr[row] = d;
        }
        __syncthreads();
        float sc = -1e30f;
        if (tid < 256) {
            sc = scr[tid];
            float m = wave_red_max(sc);
            if ((tid & 63) == 0) red[tid >> 6] = m;
        }
        __syncthreads();
        float M2 = fmaxf(fmaxf(red[0], red[1]), fmaxf(red[2], red[3]));
        if (tid < 256) {
            float e2 = __expf(sc - M2);
            s_bf[tid] = f2bf(e2);
            float sm = wave_red_sum(e2);
            if ((tid & 63) == 0) red[8 + (tid >> 6)] = sm;
        }
        __syncthreads();
        float invS = __builtin_amdgcn_rcpf(red[8] + red[9] + red[10] + red[11]);

        // ---- s4: ctx channels 0..255 → rin_s[256..511] ----
        #pragma unroll
        for (int it = 0; it < 8; it++) {
            int row = it * 32 + hwid;
            u16x8 e = *reinterpret_cast<const u16x8*>(enc_t + ((size_t)b * 256 + row) * 256 + l32 * 8);
            u16x8 ss = *reinterpret_cast<const u16x8*>(s_bf + l32 * 8);
            float d = 0.f;
            #pragma unroll
            for (int j = 0; j < 8; j++) d += bf2f(ss[j]) * bf2f(e[j]);
            d = half_red_sum(d);
            if (l32 == 0) rin_s[256 + row] = f2bf(d * invS);
        }
        // ---- s4b: positional channels → rin_s[512..551] ----
        #pragma unroll
        for (int it = 0; it < 2; it++) {
            int row = it * 32 + hwid;
            float d = 0.f;
            if (row < 40) {
                u16x8 p = *reinterpret_cast<const u16x8*>(pos2t + (size_t)row * 256 + l32 * 8);
                u16x8 ss = *reinterpret_cast<const u16x8*>(s_bf + l32 * 8);
                #pragma unroll
                for (int j = 0; j < 8; j++) d += bf2f(ss[j]) * bf2f(p[j]);
            }
            d = half_red_sum(d);
            if (l32 == 0 && row < 40) rin_s[512 + row] = f2bf(d * invS);
        }
        // ---- s5: word embedding → rin_s[0..255] ----
        if (tid < 256) {
            int tok = (t == 0) ? 0 : dec_tgt[b * T + (t - 1)];
            rin_s[tid] = E_bf[(size_t)tok * 256 + tid];
        }
        __syncthreads();

        // ---- s6: GEMV1  gi[768] = WgT1^T(576x768) · rin_s[0..575], K-split 16 waves ----
        {
            const int k0 = wave * 36;
            float acc[6][2];
            #pragma unroll
            for (int c = 0; c < 6; c++) { acc[c][0] = 0.f; acc[c][1] = 0.f; }
            #pragma unroll 4
            for (int kk = 0; kk < 36; kk++) {
                int k = k0 + kk;
                float a = bf2f(rin_s[k]);
                const unsigned int* wr = reinterpret_cast<const unsigned int*>(
                    WgT1 + (size_t)k * 768) + lane;
                #pragma unroll
                for (int c = 0; c < 6; c++) {
                    unsigned int w2 = wr[c * 64];
                    acc[c][0] = fmaf(a, __uint_as_float(w2 << 16), acc[c][0]);
                    acc[c][1] = fmaf(a, __uint_as_float(w2 & 0xffff0000u), acc[c][1]);
                }
            }
            #pragma unroll
            for (int c = 0; c < 6; c++)
                *reinterpret_cast<float2*>(&parts[wave][c * 128 + lane * 2]) =
                    make_float2(acc[c][0], acc[c][1]);
        }
        __syncthreads();
        if (tid < 768) {
            float s = 0.f;
            #pragma unroll
            for (int w = 0; w < 16; w++) s += parts[w][tid];
            gi_s[tid] = s;
        }
        __syncthreads();

        // ---- s7: GEMV2  gh[768] = WgT2^T(256x768) · h ----
        {
            const int k0 = wave * 16;
            float acc[6][2];
            #pragma unroll
            for (int c = 0; c < 6; c++) { acc[c][0] = 0.f; acc[c][1] = 0.f; }
            #pragma unroll 4
            for (int kk = 0; kk < 16; kk++) {
                int k = k0 + kk;
                float a = bf2f(hS_bf[k]);
                const unsigned int* wr = reinterpret_cast<const unsigned int*>(
                    WgT2 + (size_t)k * 768) + lane;
                #pragma unroll
                for (int c = 0; c < 6; c++) {
                    unsigned int w2 = wr[c * 64];
                    acc[c][0] = fmaf(a, __uint_as_float(w2 << 16), acc[c][0]);
                    acc[c][1] = fmaf(a, __uint_as_float(w2 & 0xffff0000u), acc[c][1]);
                }
            }
            #pragma unroll
            for (int c = 0; c < 6; c++)
                *reinterpret_cast<float2*>(&parts[wave][c * 128 + lane * 2]) =
                    make_float2(acc[c][0], acc[c][1]);
        }
        __syncthreads();
        if (tid < 768) {
            float s = 0.f;
            #pragma unroll
            for (int w = 0; w < 16; w++) s += parts[w][tid];
            gh_s[tid] = s;
        }
    }

    if (tid == 0) nllG[b] = nllA[0];
}

// ---------------- loss = 0.2 * mean_b(nll) ----------------
__global__ void k_reduce(const float* __restrict__ nll, float* __restrict__ out) {
    __shared__ float red[2];
    float v = nll[threadIdx.x];
    v = wave_red_sum(v);
    if ((threadIdx.x & 63) == 0) red[threadIdx.x >> 6] = v;
    __syncthreads();
    if (threadIdx.x == 0) out[0] = 0.2f * (red[0] + red[1]) * (1.f / 128.f);
}

extern "C" void kernel_launch(void* const* d_in, const int* in_sizes, int n_in,
                              void* d_out, int out_size, void* d_ws, size_t ws_size,
                              hipStream_t stream) {
    const float* x        = (const float*)d_in[0];
    const int*   dec_tgt  = (const int*)d_in[1];
    const int*   word_tgt = (const int*)d_in[2];
    const float* conv_w   = (const float*)d_in[3];
    const float* conv_b   = (const float*)d_in[4];
    const float* emb_dec  = (const float*)d_in[5];
    const float* word_w   = (const float*)d_in[6];
    const float* word_b   = (const float*)d_in[7];
    const float* attn_w   = (const float*)d_in[8];
    const float* attn_b   = (const float*)d_in[9];
    const float* attn_v   = (const float*)d_in[10];
    const float* gru_wih  = (const float*)d_in[11];
    const float* gru_bih  = (const float*)d_in[12];
    const float* gru_whh  = (const float*)d_in[13];
    const float* gru_bhh  = (const float*)d_in[14];
    const float* out_w    = (const float*)d_in[15];
    const float* out_b    = (const float*)d_in[16];
    const float* x_emb    = (const float*)d_in[17];
    const float* y_emb    = (const float*)d_in[18];

    char* ws = (char*)d_ws;
    size_t off = 0;
    auto alloc = [&](size_t bytes) -> void* {
        void* p = ws + off;
        off = (off + bytes + 255) & ~(size_t)255;
        return p;
    };
    unsigned short* Xt     = (unsigned short*)alloc((size_t)B * 16 * 64 * 256 * 2);  // 67MB
    unsigned short* enc_bf = (unsigned short*)alloc((size_t)B * L * CENC * 2);        // 19.4MB
    unsigned short* Wt     = (unsigned short*)alloc((size_t)9 * 256 * 256 * 2);
    unsigned short* E_bf   = (unsigned short*)alloc((size_t)NC * HID * 2);
    unsigned short* wA_bf  = (unsigned short*)alloc((size_t)HID * HID * 2);
    unsigned short* ow_bf  = (unsigned short*)alloc((size_t)NC * HID * 2);
    unsigned short* WgT1   = (unsigned short*)alloc((size_t)576 * 768 * 2);
    unsigned short* WgT2   = (unsigned short*)alloc((size_t)256 * 768 * 2);
    unsigned short* pos2t  = (unsigned short*)alloc((size_t)40 * 256 * 2);
    float* nllG   = (float*)alloc((size_t)B * 4);
    // ep_t / enc_t alias Xt (dead after k_convmm)
    unsigned short* ep_t  = Xt;
    unsigned short* enc_t = Xt + (size_t)B * L * HID;
    float* out    = (float*)d_out;

    hipLaunchKernelGGL(k_upsxt, dim3(16, 128), dim3(256), 0, stream, x, Xt);
    hipLaunchKernelGGL(k_wt, dim3(2304), dim3(256), 0, stream, conv_w, Wt);
    hipLaunchKernelGGL(k_encpos, dim3(128), dim3(256), 0, stream, x_emb, y_emb, enc_bf, pos2t);
    hipLaunchKernelGGL(k_convmm, dim3(1024, 2), dim3(256), 0, stream, Xt, Wt, conv_b, enc_bf);
    hipLaunchKernelGGL(k_etab, dim3(163), dim3(256), 0, stream, emb_dec, word_w, word_b, E_bf);
    hipLaunchKernelGGL(k_prep, dim3(256), dim3(256), 0, stream, attn_w, out_w, wA_bf, ow_bf);
    hipLaunchKernelGGL(k_wg, dim3(832), dim3(768), 0, stream, gru_wih, gru_whh, WgT1, WgT2);
    hipLaunchKernelGGL(k_ep, dim3(2, 8, 128), dim3(256), 0, stream, enc_bf, attn_w, ep_t);
    hipLaunchKernelGGL(k_enct, dim3(4, 128), dim3(256), 0, stream, enc_bf, enc_t);
    hipLaunchKernelGGL(k_loop, dim3(128), dim3(1024), 0, stream,
                       ep_t, enc_t, wA_bf, ow_bf, E_bf, pos2t, WgT1, WgT2,
                       attn_b, attn_v, out_b, gru_bih, gru_bhh, dec_tgt, word_tgt, nllG);
    hipLaunchKernelGGL(k_reduce, dim3(1), dim3(128), 0, stream, nllG, out);
}

// Round 7
// 1669.091 us; speedup vs baseline: 2.9383x; 2.9383x over previous
//
#include <hip/hip_runtime.h>
#include <hip/hip_bf16.h>
#include <math.h>

#define B    128
#define CIN  256
#define HIN  8
#define WIN_ 32
#define RH   16
#define RW   64
#define HID  256
#define NC   163
#define T    32
#define L    256
#define CENC 296
#define RINW 576   // [0..295 ctx][296..319 pad(weight-zeroed)][320..575 h]

typedef __attribute__((ext_vector_type(8))) short short8;
typedef __attribute__((ext_vector_type(8))) unsigned short u16x8;
typedef __attribute__((ext_vector_type(4))) float f32x4;

__device__ __forceinline__ float bf2f(unsigned short u) {
    unsigned int x = ((unsigned int)u) << 16;
    return __uint_as_float(x);
}
__device__ __forceinline__ unsigned short f2bf(float f) {
    unsigned int x = __float_as_uint(f);
    unsigned int r = (x + 0x7FFFu + ((x >> 16) & 1u)) >> 16;
    return (unsigned short)r;
}
__device__ __forceinline__ float fast_tanh(float x) {
    float e = __expf(2.f * x);
    return 1.f - 2.f * __builtin_amdgcn_rcpf(e + 1.f);
}
__device__ __forceinline__ float fast_sigm(float x) {
    return __builtin_amdgcn_rcpf(1.f + __expf(-x));
}
__device__ __forceinline__ float wave_red_max(float v) {
    #pragma unroll
    for (int o = 32; o > 0; o >>= 1) v = fmaxf(v, __shfl_down(v, o, 64));
    return v;
}
__device__ __forceinline__ float wave_red_sum(float v) {
    #pragma unroll
    for (int o = 32; o > 0; o >>= 1) v += __shfl_down(v, o, 64);
    return v;
}
__device__ __forceinline__ float half_red_sum(float v) {
    #pragma unroll
    for (int o = 16; o > 0; o >>= 1) v += __shfl_down(v, o, 64);
    return v;
}

// ---------------- init: zero nll ----------------
__global__ void k_init(float* __restrict__ nllG) {
    if (threadIdx.x < B) nllG[threadIdx.x] = 0.f;
}

// ---------------- bilinear upsample fused with transpose → Xt[b][y][x][ci] bf16 ----------------
__global__ void __launch_bounds__(256) k_upsxt(const float* __restrict__ x,
                                               unsigned short* __restrict__ Xt) {
    __shared__ __align__(16) float sf[64 * 2 * 32];
    const int y = blockIdx.x;
    const int b = blockIdx.y;
    const int tid = threadIdx.x;
    float sy = 0.5f * y - 0.25f;
    int yq0 = (y - 1) >> 1;
    float wy = sy - (float)yq0;
    int y0c = min(max(yq0, 0), HIN - 1);
    int y1c = min(max(yq0 + 1, 0), HIN - 1);
    const int xo = tid & 63;
    const int cj = tid >> 6;
    float sx = 0.5f * xo - 0.25f;
    int xq0 = (xo - 1) >> 1;
    float wx = sx - (float)xq0;
    int x0c = min(max(xq0, 0), WIN_ - 1);
    int x1c = min(max(xq0 + 1, 0), WIN_ - 1);
    for (int cc = 0; cc < 4; cc++) {
        __syncthreads();
        #pragma unroll
        for (int i = 0; i < 4; i++) {
            int idx = tid * 4 + i;
            int c = idx >> 4;
            int rowh = (idx >> 3) & 1;
            int part = idx & 7;
            int ysrc = rowh ? y1c : y0c;
            float4 v = *reinterpret_cast<const float4*>(
                x + ((size_t)(b * CIN + cc * 64 + c) * HIN + ysrc) * WIN_ + part * 4);
            *reinterpret_cast<float4*>(sf + ((c * 2 + rowh) * 32 + part * 4)) = v;
        }
        __syncthreads();
        unsigned short ov[16];
        #pragma unroll
        for (int j = 0; j < 16; j++) {
            int c = cj * 16 + j;
            const float* r0 = sf + (c * 2 + 0) * 32;
            const float* r1 = sf + (c * 2 + 1) * 32;
            float v = (1.f - wy) * ((1.f - wx) * r0[x0c] + wx * r0[x1c])
                    +        wy  * ((1.f - wx) * r1[x0c] + wx * r1[x1c]);
            ov[j] = f2bf(v);
        }
        unsigned short* dst = Xt + ((size_t)((b * 16 + y) * 64 + xo)) * 256 + cc * 64 + cj * 16;
        *reinterpret_cast<u16x8*>(dst)     = *reinterpret_cast<u16x8*>(ov);
        *reinterpret_cast<u16x8*>(dst + 8) = *reinterpret_cast<u16x8*>(ov + 8);
    }
}

// ---------------- weight transform: Wt[s][co][ci] bf16 ----------------
__global__ void k_wt(const float* __restrict__ conv_w, unsigned short* __restrict__ Wt) {
    int e = blockIdx.x * 256 + threadIdx.x;
    int ci = e & 255;
    int co = (e >> 8) & 255;
    int s  = e >> 16;
    Wt[(size_t)(s * 256 + co) * 256 + ci] = f2bf(conv_w[(size_t)(co * 256 + ci) * 9 + s]);
}

// ---------------- conv3x3 MFMA implicit GEMM + fused bias/ReLU/pool → enc_bf ----------------
__global__ void __launch_bounds__(256) k_convmm(const unsigned short* __restrict__ Xt,
        const unsigned short* __restrict__ Wt, const float* __restrict__ conv_b,
        unsigned short* __restrict__ enc_bf) {
    __shared__ __align__(16) char smem[34048];
    unsigned short* A_s = (unsigned short*)smem;
    unsigned short* B_s = A_s + 128 * 40;
    float* pool = (float*)smem;
    const int mt = blockIdx.x;
    const int n0 = blockIdx.y * 128;
    const int b = mt >> 3;
    const int y0 = (mt & 7) * 2;
    const int tid = threadIdx.x;
    const int wave = tid >> 6, lane = tid & 63;
    const int mq = (wave & 1) * 64, nq = (wave >> 1) * 64;
    const int lm = lane & 15, lq = lane >> 4;
    f32x4 acc[4][4];
    #pragma unroll
    for (int mi = 0; mi < 4; mi++)
        #pragma unroll
        for (int ni = 0; ni < 4; ni++)
            #pragma unroll
            for (int r = 0; r < 4; r++) acc[mi][ni][r] = 0.f;

    for (int s9 = 0; s9 < 9; s9++) {
        const int ky = s9 / 3, kx = s9 % 3;
        const unsigned short* Wb = Wt + (size_t)s9 * 256 * 256;
        for (int kc = 0; kc < 256; kc += 32) {
            __syncthreads();
            #pragma unroll
            for (int it = 0; it < 2; it++) {
                int s2 = tid + it * 256;
                int pix = s2 >> 2, q4 = s2 & 3;
                int yy = y0 + (pix >> 6) + ky - 1;
                int xx = (pix & 63) + kx - 1;
                u16x8 va = {0, 0, 0, 0, 0, 0, 0, 0};
                if ((unsigned)yy < 16u && (unsigned)xx < 64u)
                    va = *reinterpret_cast<const u16x8*>(
                        Xt + ((size_t)((b * 16 + yy) * 64 + xx)) * 256 + kc + q4 * 8);
                *reinterpret_cast<u16x8*>(A_s + pix * 40 + q4 * 8) = va;
                u16x8 vb = *reinterpret_cast<const u16x8*>(
                    Wb + (size_t)(n0 + pix) * 256 + kc + q4 * 8);
                *reinterpret_cast<u16x8*>(B_s + pix * 40 + q4 * 8) = vb;
            }
            __syncthreads();
            short8 af[4], bfr[4];
            #pragma unroll
            for (int mi = 0; mi < 4; mi++)
                af[mi] = *reinterpret_cast<const short8*>(A_s + (mq + mi * 16 + lm) * 40 + lq * 8);
            #pragma unroll
            for (int ni = 0; ni < 4; ni++)
                bfr[ni] = *reinterpret_cast<const short8*>(B_s + (nq + ni * 16 + lm) * 40 + lq * 8);
            #pragma unroll
            for (int mi = 0; mi < 4; mi++)
                #pragma unroll
                for (int ni = 0; ni < 4; ni++)
                    acc[mi][ni] = __builtin_amdgcn_mfma_f32_16x16x32_bf16(
                        af[mi], bfr[ni], acc[mi][ni], 0, 0, 0);
        }
    }
    __syncthreads();
    #pragma unroll
    for (int mi = 0; mi < 4; mi++) {
        int px0 = mi * 8 + lq * 2;
        #pragma unroll
        for (int ni = 0; ni < 4; ni++) {
            int nl = nq + ni * 16 + lm;
            float pa = fmaxf(acc[mi][ni][0], acc[mi][ni][1]);
            float pb = fmaxf(acc[mi][ni][2], acc[mi][ni][3]);
            pool[((wave & 1) * 32 + px0) * 132 + nl] = pa;
            pool[((wave & 1) * 32 + px0 + 1) * 132 + nl] = pb;
        }
    }
    __syncthreads();
    {
        int base = tid * 16;
        int px = base >> 7;
        int nb = base & 127;
        unsigned short ov[16];
        #pragma unroll
        for (int i = 0; i < 16; i++) {
            int n = nb + i;
            float v = fmaxf(pool[px * 132 + n], pool[(32 + px) * 132 + n]) + conv_b[n0 + n];
            ov[i] = f2bf(fmaxf(v, 0.f));
        }
        unsigned short* dst = enc_bf + ((size_t)b * L + (mt & 7) * 32 + px) * CENC + n0 + nb;
        *reinterpret_cast<u16x8*>(dst)     = *reinterpret_cast<u16x8*>(ov);
        *reinterpret_cast<u16x8*>(dst + 8) = *reinterpret_cast<u16x8*>(ov + 8);
    }
}

// ---------------- positional channels (bf16) + pos2t[40][256] bf16 ----------------
__global__ void k_encpos(const float* __restrict__ x_emb, const float* __restrict__ y_emb,
                         unsigned short* __restrict__ enc_bf, unsigned short* __restrict__ pos2t) {
    int b = blockIdx.x, l = threadIdx.x;
    int yl = l >> 5, xl = l & 31;
    unsigned short* e = enc_bf + (size_t)(b * L + l) * CENC + 256;
    #pragma unroll
    for (int c = 0; c < 32; c++) e[c] = f2bf(x_emb[xl * 32 + c]);
    #pragma unroll
    for (int c = 0; c < 8; c++) e[32 + c] = f2bf(y_emb[yl * 8 + c]);
    if (b == 0) {
        #pragma unroll
        for (int c = 0; c < 32; c++) pos2t[c * 256 + l] = f2bf(x_emb[xl * 32 + c]);
        #pragma unroll
        for (int c = 0; c < 8; c++) pos2t[(32 + c) * 256 + l] = f2bf(y_emb[yl * 8 + c]);
    }
}

// ---------------- enc_t[b][c][l] bf16 ----------------
__global__ void __launch_bounds__(256) k_enct(const unsigned short* __restrict__ enc_bf,
                                              unsigned short* __restrict__ enc_t) {
    __shared__ unsigned short s[64 * 264];
    const int c0 = blockIdx.x * 64;
    const int b = blockIdx.y;
    const int tid = threadIdx.x;
    #pragma unroll
    for (int j = 0; j < 8; j++) {
        u16x8 u = *reinterpret_cast<const u16x8*>(
            enc_bf + ((size_t)b * L + tid) * CENC + c0 + j * 8);
        #pragma unroll
        for (int k = 0; k < 8; k++) s[(j * 8 + k) * 264 + tid] = u[k];
    }
    __syncthreads();
    {
        int c = tid >> 2, lp = tid & 3;
        const unsigned short* row = s + c * 264 + lp * 64;
        unsigned short* dst = enc_t + ((size_t)b * 256 + c0 + c) * L + lp * 64;
        #pragma unroll
        for (int i = 0; i < 8; i++)
            *reinterpret_cast<u16x8*>(dst + i * 8) =
                *reinterpret_cast<const u16x8*>(row + i * 8);
    }
}

// ---------------- E[v][h] fp32 ----------------
__global__ void __launch_bounds__(256) k_etab(const float* __restrict__ emb_dec,
                                              const float* __restrict__ word_w,
                                              const float* __restrict__ word_b,
                                              float* __restrict__ E) {
    __shared__ float er[NC];
    int row = blockIdx.x, tid = threadIdx.x;
    for (int k = tid; k < NC; k += 256) er[k] = emb_dec[(size_t)row * NC + k];
    __syncthreads();
    float a = word_b[tid];
    for (int k = 0; k < NC; k++) a += er[k] * word_w[(size_t)tid * NC + k];
    E[(size_t)row * HID + tid] = a;
}

// ---------------- row-major bf16 weight casts ----------------
__global__ void k_prep(const float* __restrict__ attn_w, const float* __restrict__ out_w,
                       unsigned short* __restrict__ wA_bf, unsigned short* __restrict__ ow_bf) {
    int o = blockIdx.x, k = threadIdx.x;
    wA_bf[(size_t)o * 256 + k] = f2bf(attn_w[(size_t)o * 552 + k]);
    if (o < NC) ow_bf[(size_t)o * 256 + k] = f2bf(out_w[(size_t)o * 256 + k]);
}

// ---------------- GRU weight prep ----------------
// Wg1n[768][320]: ctx part (wih cols 256..551, zero-pad 296..319); Wg2[768][256]: whh.
__global__ void __launch_bounds__(576) k_wg(const float* __restrict__ wih,
                                            const float* __restrict__ whh,
                                            unsigned short* __restrict__ Wg1n,
                                            unsigned short* __restrict__ Wg2) {
    int g = blockIdx.x, k = threadIdx.x;
    if (k < 320) {
        Wg1n[(size_t)g * 320 + k] = (k < 296) ? f2bf(wih[(size_t)g * 552 + 256 + k]) : 0;
    } else {
        int k2 = k - 320;
        Wg2[(size_t)g * 256 + k2] = f2bf(whh[(size_t)g * 256 + k2]);
    }
}
// WgE[k][g] = wih[g][k] (k<256, emb part, k-major bf16)
__global__ void __launch_bounds__(768) k_wge(const float* __restrict__ wih,
                                             unsigned short* __restrict__ WgE) {
    int k = blockIdx.x, g = threadIdx.x;
    WgE[(size_t)k * 768 + g] = f2bf(wih[(size_t)g * 552 + k]);
}
// giE[v][g] = sum_k WgE[k][g]*E[v][k] + bih[g]   (emb contribution of gi, per vocab)
__global__ void __launch_bounds__(768) k_gie(const float* __restrict__ E,
                                             const unsigned short* __restrict__ WgE,
                                             const float* __restrict__ bih,
                                             float* __restrict__ giE) {
    __shared__ float er[256];
    int v = blockIdx.x, g = threadIdx.x;
    if (g < 256) er[g] = E[(size_t)v * 256 + g];
    __syncthreads();
    float a = bih[g];
    #pragma unroll 4
    for (int k = 0; k < 256; k++) a += er[k] * bf2f(WgE[(size_t)k * 768 + g]);
    giE[(size_t)v * 768 + g] = a;
}

// ---------------- ep_t[b][l][h] bf16 ----------------
__global__ void __launch_bounds__(256) k_ep(const unsigned short* __restrict__ enc_bf,
                                            const float* __restrict__ attn_w,
                                            unsigned short* __restrict__ ep_t) {
    __shared__ __align__(16) float eS[16][132];
    __shared__ __align__(16) float wS[16][36];
    const int l0 = blockIdx.x * 128;
    const int h0 = blockIdx.y * 32;
    const int b = blockIdx.z;
    const int tid = threadIdx.x;
    const int hh = tid >> 5, ll = tid & 31;
    float acc[4][4];
    #pragma unroll
    for (int s2 = 0; s2 < 4; s2++)
        #pragma unroll
        for (int r = 0; r < 4; r++) acc[s2][r] = 0.f;
    for (int kc = 0; kc < CENC; kc += 16) {
        const int kn = min(16, CENC - kc);
        __syncthreads();
        #pragma unroll
        for (int it = 0; it < 2; it++) {
            int idx = it * 256 + tid;
            int lq = idx >> 2, kq = idx & 3;
            float v0 = 0.f, v1 = 0.f, v2 = 0.f, v3 = 0.f;
            if (kq * 4 < kn) {
                ushort4 u = *reinterpret_cast<const ushort4*>(
                    enc_bf + (size_t)(b * L + l0 + lq) * CENC + kc + kq * 4);
                v0 = bf2f(u.x); v1 = bf2f(u.y); v2 = bf2f(u.z); v3 = bf2f(u.w);
            }
            eS[kq * 4 + 0][lq] = v0; eS[kq * 4 + 1][lq] = v1;
            eS[kq * 4 + 2][lq] = v2; eS[kq * 4 + 3][lq] = v3;
        }
        if (tid < 128) {
            int hq = tid >> 2, kq = tid & 3;
            float4 v = make_float4(0.f, 0.f, 0.f, 0.f);
            if (kq * 4 < kn)
                v = *reinterpret_cast<const float4*>(attn_w + (size_t)(h0 + hq) * 552 + 256 + kc + kq * 4);
            wS[kq * 4 + 0][hq] = v.x; wS[kq * 4 + 1][hq] = v.y;
            wS[kq * 4 + 2][hq] = v.z; wS[kq * 4 + 3][hq] = v.w;
        }
        __syncthreads();
        #pragma unroll
        for (int k = 0; k < 16; k++) {
            float4 e = *reinterpret_cast<const float4*>(&eS[k][ll * 4]);
            float4 w = *reinterpret_cast<const float4*>(&wS[k][hh * 4]);
            float ev[4] = {e.x, e.y, e.z, e.w};
            float wv[4] = {w.x, w.y, w.z, w.w};
            #pragma unroll
            for (int s2 = 0; s2 < 4; s2++)
                #pragma unroll
                for (int r = 0; r < 4; r++) acc[s2][r] += wv[s2] * ev[r];
        }
    }
    #pragma unroll
    for (int r = 0; r < 4; r++) {
        ushort4 o;
        o.x = f2bf(acc[0][r]); o.y = f2bf(acc[1][r]);
        o.z = f2bf(acc[2][r]); o.w = f2bf(acc[3][r]);
        *reinterpret_cast<ushort4*>(
            ep_t + ((size_t)(b * L) + l0 + ll * 4 + r) * HID + h0 + hh * 4) = o;
    }
}

// ---------------- per-step phase A: pointwise + nll + attention (half-wave rows) ----------------
__global__ void __launch_bounds__(1024) k_stepA(int t,
        float* __restrict__ hbuf, const float* __restrict__ gbuf,
        const float* __restrict__ giE, const float* __restrict__ bhh,
        const unsigned short* __restrict__ ep_t, const unsigned short* __restrict__ enc_t,
        const unsigned short* __restrict__ wA_bf, const unsigned short* __restrict__ ow_bf,
        const unsigned short* __restrict__ pos2t, const float* __restrict__ attn_b,
        const float* __restrict__ attn_v, const float* __restrict__ out_b,
        const int* __restrict__ dec_tgt, const int* __restrict__ word_tgt,
        unsigned short* __restrict__ rin, float* __restrict__ nllG) {
    const int b = blockIdx.x;
    const int tid = threadIdx.x;
    const int hwid = tid >> 5, l32 = tid & 31;

    __shared__ unsigned short hS_bf[256], hp_bf[256], v_bf[256], s_bf[256];
    __shared__ float scr[256];
    __shared__ float red[16];

    if (tid < 256) v_bf[tid] = f2bf(attn_v[tid]);

    // ---- s0: GRU pointwise h_t ----
    if (tid < 256) {
        float h;
        if (t == 0) {
            h = 0.f;
        } else {
            float hold = hbuf[(size_t)b * HID + tid];
            int tokp = (t == 1) ? 0 : dec_tgt[b * T + (t - 2)];
            const float* gE = giE + (size_t)tokp * 768;
            const float* g0 = gbuf + (size_t)b * 768;
            const float* g1 = gbuf + 98304 + (size_t)b * 768;
            float ir = g0[tid] + gE[tid];
            float iz = g0[256 + tid] + gE[256 + tid];
            float in_ = g0[512 + tid] + gE[512 + tid];
            float hr = g1[tid] + bhh[tid];
            float hz = g1[256 + tid] + bhh[256 + tid];
            float hn = g1[512 + tid] + bhh[512 + tid];
            float r_ = fast_sigm(ir + hr);
            float z_ = fast_sigm(iz + hz);
            float n_ = fast_tanh(in_ + r_ * hn);
            h = (1.f - z_) * n_ + z_ * hold;
        }
        hbuf[(size_t)b * HID + tid] = h;
        unsigned short hb = f2bf(h);
        hS_bf[tid] = hb;
        rin[(size_t)b * RINW + 320 + tid] = hb;
    }
    __syncthreads();

    // ---- s1 (t>0): logits(h_t) + nll vs word_targets[t-1] ----
    if (t > 0) {
        #pragma unroll
        for (int it = 0; it < 6; it++) {
            int row = it * 32 + hwid;
            float d = 0.f;
            if (row < NC) {
                u16x8 w = *reinterpret_cast<const u16x8*>(ow_bf + (size_t)row * 256 + l32 * 8);
                u16x8 hh = *reinterpret_cast<const u16x8*>(hS_bf + l32 * 8);
                #pragma unroll
                for (int j = 0; j < 8; j++) d += bf2f(w[j]) * bf2f(hh[j]);
            }
            d = half_red_sum(d);
            if (l32 == 0 && row < NC) scr[row] = d + out_b[row];
        }
        __syncthreads();
        float lg = -1e30f;
        if (tid < 256) {
            if (tid < NC) lg = scr[tid];
            float m = wave_red_max(lg);
            if ((tid & 63) == 0) red[tid >> 6] = m;
        }
        __syncthreads();
        float M = fmaxf(fmaxf(red[0], red[1]), fmaxf(red[2], red[3]));
        if (tid < 256) {
            float e = (tid < NC) ? __expf(lg - M) : 0.f;
            float sm = wave_red_sum(e);
            if ((tid & 63) == 0) red[8 + (tid >> 6)] = sm;
        }
        __syncthreads();
        if (tid == 0) {
            float S = red[8] + red[9] + red[10] + red[11];
            int tgt = word_tgt[b * T + (t - 1)];
            if (tgt >= 0) nllG[b] += M + __logf(S) - scr[tgt];
        }
        __syncthreads();
    }

    // ---- s2: hp = h @ Wh^T + attn_b ----
    #pragma unroll
    for (int it = 0; it < 8; it++) {
        int row = it * 32 + hwid;
        u16x8 w = *reinterpret_cast<const u16x8*>(wA_bf + (size_t)row * 256 + l32 * 8);
        u16x8 hh = *reinterpret_cast<const u16x8*>(hS_bf + l32 * 8);
        float d = 0.f;
        #pragma unroll
        for (int j = 0; j < 8; j++) d += bf2f(w[j]) * bf2f(hh[j]);
        d = half_red_sum(d);
        if (l32 == 0) hp_bf[row] = f2bf(d + attn_b[row]);
    }
    __syncthreads();

    // ---- s3: scores over l ----
    #pragma unroll
    for (int it = 0; it < 8; it++) {
        int row = it * 32 + hwid;
        u16x8 e = *reinterpret_cast<const u16x8*>(ep_t + ((size_t)b * L + row) * 256 + l32 * 8);
        u16x8 hp = *reinterpret_cast<const u16x8*>(hp_bf + l32 * 8);
        u16x8 vv = *reinterpret_cast<const u16x8*>(v_bf + l32 * 8);
        float d = 0.f;
        #pragma unroll
        for (int j = 0; j < 8; j++)
            d += bf2f(vv[j]) * fast_tanh(bf2f(e[j]) + bf2f(hp[j]));
        d = half_red_sum(d);
        if (l32 == 0) scr[row] = d;
    }
    __syncthreads();
    float sc = -1e30f;
    if (tid < 256) {
        sc = scr[tid];
        float m = wave_red_max(sc);
        if ((tid & 63) == 0) red[tid >> 6] = m;
    }
    __syncthreads();
    float M2 = fmaxf(fmaxf(red[0], red[1]), fmaxf(red[2], red[3]));
    if (tid < 256) {
        float e2 = __expf(sc - M2);
        s_bf[tid] = f2bf(e2);
        float sm = wave_red_sum(e2);
        if ((tid & 63) == 0) red[8 + (tid >> 6)] = sm;
    }
    __syncthreads();
    float invS = __builtin_amdgcn_rcpf(red[8] + red[9] + red[10] + red[11]);

    // ---- s4: ctx channels 0..255 → rin[0..255] ----
    #pragma unroll
    for (int it = 0; it < 8; it++) {
        int row = it * 32 + hwid;
        u16x8 e = *reinterpret_cast<const u16x8*>(enc_t + ((size_t)b * 256 + row) * 256 + l32 * 8);
        u16x8 ss = *reinterpret_cast<const u16x8*>(s_bf + l32 * 8);
        float d = 0.f;
        #pragma unroll
        for (int j = 0; j < 8; j++) d += bf2f(ss[j]) * bf2f(e[j]);
        d = half_red_sum(d);
        if (l32 == 0) rin[(size_t)b * RINW + row] = f2bf(d * invS);
    }
    // ---- s4b: positional channels → rin[256..295] ----
    #pragma unroll
    for (int it = 0; it < 2; it++) {
        int row = it * 32 + hwid;
        float d = 0.f;
        if (row < 40) {
            u16x8 p = *reinterpret_cast<const u16x8*>(pos2t + (size_t)row * 256 + l32 * 8);
            u16x8 ss = *reinterpret_cast<const u16x8*>(s_bf + l32 * 8);
            #pragma unroll
            for (int j = 0; j < 8; j++) d += bf2f(ss[j]) * bf2f(p[j]);
        }
        d = half_red_sum(d);
        if (l32 == 0 && row < 40) rin[(size_t)b * RINW + 256 + row] = f2bf(d * invS);
    }
}

// ---------------- per-step phase B: gate GEMMs, 24 blocks (M=128, N=64) ----------------
// blocks 0..11: gi-ctx (K=320, weights zero-padded); blocks 12..23: gh (K=256)
__global__ void __launch_bounds__(256) k_stepB(const unsigned short* __restrict__ rin,
        const unsigned short* __restrict__ Wg1n, const unsigned short* __restrict__ Wg2,
        float* __restrict__ gbuf) {
    __shared__ __align__(16) unsigned short A_s[128 * 40];
    __shared__ __align__(16) unsigned short B_s[64 * 40];
    const int nt = blockIdx.x;
    const int half = (nt >= 12) ? 1 : 0;
    const int n0 = (nt - half * 12) * 64;
    const int K = half ? 256 : 320;
    const int Aoff = half ? 320 : 0;
    const unsigned short* W = half ? Wg2 : Wg1n;
    const int Wst = half ? 256 : 320;
    const int tid = threadIdx.x;
    const int wave = tid >> 6, lane = tid & 63;
    const int mq = (wave & 1) * 64, nq = (wave >> 1) * 32;
    const int lm = lane & 15, lq = lane >> 4;
    f32x4 acc[4][2];
    #pragma unroll
    for (int mi = 0; mi < 4; mi++)
        #pragma unroll
        for (int ni = 0; ni < 2; ni++)
            #pragma unroll
            for (int r = 0; r < 4; r++) acc[mi][ni][r] = 0.f;
    for (int kc = 0; kc < K; kc += 32) {
        __syncthreads();
        #pragma unroll
        for (int it = 0; it < 3; it++) {
            int s2 = tid + it * 256;          // 0..767: 512 A-slots + 256 B-slots
            if (s2 < 512) {
                int row = s2 >> 2, q4 = s2 & 3;
                *reinterpret_cast<u16x8*>(A_s + row * 40 + q4 * 8) =
                    *reinterpret_cast<const u16x8*>(rin + (size_t)row * RINW + Aoff + kc + q4 * 8);
            } else {
                int i = s2 - 512;
                int row = i >> 2, q4 = i & 3;
                *reinterpret_cast<u16x8*>(B_s + row * 40 + q4 * 8) =
                    *reinterpret_cast<const u16x8*>(W + (size_t)(n0 + row) * Wst + kc + q4 * 8);
            }
        }
        __syncthreads();
        short8 af[4], bfr[2];
        #pragma unroll
        for (int mi = 0; mi < 4; mi++)
            af[mi] = *reinterpret_cast<const short8*>(A_s + (mq + mi * 16 + lm) * 40 + lq * 8);
        #pragma unroll
        for (int ni = 0; ni < 2; ni++)
            bfr[ni] = *reinterpret_cast<const short8*>(B_s + (nq + ni * 16 + lm) * 40 + lq * 8);
        #pragma unroll
        for (int mi = 0; mi < 4; mi++)
            #pragma unroll
            for (int ni = 0; ni < 2; ni++)
                acc[mi][ni] = __builtin_amdgcn_mfma_f32_16x16x32_bf16(
                    af[mi], bfr[ni], acc[mi][ni], 0, 0, 0);
    }
    float* outp = gbuf + (size_t)half * 98304;
    #pragma unroll
    for (int mi = 0; mi < 4; mi++)
        #pragma unroll
        for (int ni = 0; ni < 2; ni++) {
            int g = n0 + nq + ni * 16 + lm;
            int b0 = mq + mi * 16 + lq * 4;
            #pragma unroll
            for (int r = 0; r < 4; r++)
                outp[(size_t)(b0 + r) * 768 + g] = acc[mi][ni][r];
        }
}

// ---------------- final: pointwise h_32 + step-31 NLL ----------------
__global__ void __launch_bounds__(256) k_finalnll(const float* __restrict__ hbuf,
        const float* __restrict__ gbuf, const float* __restrict__ giE,
        const float* __restrict__ bhh, const unsigned short* __restrict__ ow_bf,
        const float* __restrict__ out_b, const int* __restrict__ dec_tgt,
        const int* __restrict__ word_tgt, float* __restrict__ nllG) {
    const int b = blockIdx.x, tid = threadIdx.x;
    __shared__ float hS[256], lgS[256];
    __shared__ float red[8];
    {
        float hold = hbuf[(size_t)b * HID + tid];
        int tokp = dec_tgt[b * T + (T - 2)];
        const float* gE = giE + (size_t)tokp * 768;
        const float* g0 = gbuf + (size_t)b * 768;
        const float* g1 = gbuf + 98304 + (size_t)b * 768;
        float r_ = fast_sigm(g0[tid] + gE[tid] + g1[tid] + bhh[tid]);
        float z_ = fast_sigm(g0[256 + tid] + gE[256 + tid] + g1[256 + tid] + bhh[256 + tid]);
        float n_ = fast_tanh(g0[512 + tid] + gE[512 + tid] + r_ * (g1[512 + tid] + bhh[512 + tid]));
        hS[tid] = (1.f - z_) * n_ + z_ * hold;
    }
    __syncthreads();
    float lg = -1e30f;
    if (tid < NC) {
        float a = out_b[tid];
        const u16x8* wp = reinterpret_cast<const u16x8*>(ow_bf + (size_t)tid * 256);
        #pragma unroll 4
        for (int c8 = 0; c8 < 32; c8++) {
            u16x8 u = wp[c8];
            #pragma unroll
            for (int j = 0; j < 8; j++) a += bf2f(u[j]) * hS[c8 * 8 + j];
        }
        lg = a;
    }
    lgS[tid] = lg;
    float m = wave_red_max(lg);
    if ((tid & 63) == 0) red[tid >> 6] = m;
    __syncthreads();
    float M = fmaxf(fmaxf(red[0], red[1]), fmaxf(red[2], red[3]));
    __syncthreads();
    float e = (tid < NC) ? __expf(lg - M) : 0.f;
    float sm = wave_red_sum(e);
    if ((tid & 63) == 0) red[tid >> 6] = sm;
    __syncthreads();
    float S = red[0] + red[1] + red[2] + red[3];
    if (tid == 0) {
        int tgt = word_tgt[b * T + (T - 1)];
        if (tgt >= 0) nllG[b] += M + __logf(S) - lgS[tgt];
    }
}

// ---------------- loss = 0.2 * mean_b(nll) ----------------
__global__ void k_reduce(const float* __restrict__ nll, float* __restrict__ out) {
    __shared__ float red[2];
    float v = nll[threadIdx.x];
    v = wave_red_sum(v);
    if ((threadIdx.x & 63) == 0) red[threadIdx.x >> 6] = v;
    __syncthreads();
    if (threadIdx.x == 0) out[0] = 0.2f * (red[0] + red[1]) * (1.f / 128.f);
}

extern "C" void kernel_launch(void* const* d_in, const int* in_sizes, int n_in,
                              void* d_out, int out_size, void* d_ws, size_t ws_size,
                              hipStream_t stream) {
    const float* x        = (const float*)d_in[0];
    const int*   dec_tgt  = (const int*)d_in[1];
    const int*   word_tgt = (const int*)d_in[2];
    const float* conv_w   = (const float*)d_in[3];
    const float* conv_b   = (const float*)d_in[4];
    const float* emb_dec  = (const float*)d_in[5];
    const float* word_w   = (const float*)d_in[6];
    const float* word_b   = (const float*)d_in[7];
    const float* attn_w   = (const float*)d_in[8];
    const float* attn_b   = (const float*)d_in[9];
    const float* attn_v   = (const float*)d_in[10];
    const float* gru_wih  = (const float*)d_in[11];
    const float* gru_bih  = (const float*)d_in[12];
    const float* gru_whh  = (const float*)d_in[13];
    const float* gru_bhh  = (const float*)d_in[14];
    const float* out_w    = (const float*)d_in[15];
    const float* out_b    = (const float*)d_in[16];
    const float* x_emb    = (const float*)d_in[17];
    const float* y_emb    = (const float*)d_in[18];

    char* ws = (char*)d_ws;
    size_t off = 0;
    auto alloc = [&](size_t bytes) -> void* {
        void* p = ws + off;
        off = (off + bytes + 255) & ~(size_t)255;
        return p;
    };
    unsigned short* Xt     = (unsigned short*)alloc((size_t)B * 16 * 64 * 256 * 2);  // 67MB
    unsigned short* enc_bf = (unsigned short*)alloc((size_t)B * L * CENC * 2);        // 19.4MB
    unsigned short* Wt     = (unsigned short*)alloc((size_t)9 * 256 * 256 * 2);
    float* E      = (float*)alloc((size_t)NC * HID * 4);
    unsigned short* wA_bf  = (unsigned short*)alloc((size_t)HID * HID * 2);
    unsigned short* ow_bf  = (unsigned short*)alloc((size_t)NC * HID * 2);
    unsigned short* Wg1n   = (unsigned short*)alloc((size_t)768 * 320 * 2);
    unsigned short* Wg2    = (unsigned short*)alloc((size_t)768 * 256 * 2);
    unsigned short* WgE    = (unsigned short*)alloc((size_t)256 * 768 * 2);
    float* giE    = (float*)alloc((size_t)NC * 768 * 4);
    unsigned short* pos2t  = (unsigned short*)alloc((size_t)40 * 256 * 2);
    unsigned short* rin    = (unsigned short*)alloc((size_t)B * RINW * 2);
    float* gbuf   = (float*)alloc((size_t)2 * B * 768 * 4);
    float* hbuf   = (float*)alloc((size_t)B * HID * 4);
    float* nllG   = (float*)alloc((size_t)B * 4);
    // ep_t / enc_t alias Xt (dead after k_convmm)
    unsigned short* ep_t  = Xt;
    unsigned short* enc_t = Xt + (size_t)B * L * HID;
    float* out    = (float*)d_out;

    hipLaunchKernelGGL(k_init, dim3(1), dim3(128), 0, stream, nllG);
    hipLaunchKernelGGL(k_upsxt, dim3(16, 128), dim3(256), 0, stream, x, Xt);
    hipLaunchKernelGGL(k_wt, dim3(2304), dim3(256), 0, stream, conv_w, Wt);
    hipLaunchKernelGGL(k_encpos, dim3(128), dim3(256), 0, stream, x_emb, y_emb, enc_bf, pos2t);
    hipLaunchKernelGGL(k_convmm, dim3(1024, 2), dim3(256), 0, stream, Xt, Wt, conv_b, enc_bf);
    hipLaunchKernelGGL(k_etab, dim3(163), dim3(256), 0, stream, emb_dec, word_w, word_b, E);
    hipLaunchKernelGGL(k_prep, dim3(256), dim3(256), 0, stream, attn_w, out_w, wA_bf, ow_bf);
    hipLaunchKernelGGL(k_wg, dim3(768), dim3(576), 0, stream, gru_wih, gru_whh, Wg1n, Wg2);
    hipLaunchKernelGGL(k_wge, dim3(256), dim3(768), 0, stream, gru_wih, WgE);
    hipLaunchKernelGGL(k_gie, dim3(163), dim3(768), 0, stream, E, WgE, gru_bih, giE);
    hipLaunchKernelGGL(k_ep, dim3(2, 8, 128), dim3(256), 0, stream, enc_bf, attn_w, ep_t);
    hipLaunchKernelGGL(k_enct, dim3(4, 128), dim3(256), 0, stream, enc_bf, enc_t);
    for (int t = 0; t < T; t++) {
        hipLaunchKernelGGL(k_stepA, dim3(128), dim3(1024), 0, stream, t,
                           hbuf, gbuf, giE, gru_bhh, ep_t, enc_t, wA_bf, ow_bf,
                           pos2t, attn_b, attn_v, out_b, dec_tgt, word_tgt, rin, nllG);
        hipLaunchKernelGGL(k_stepB, dim3(24), dim3(256), 0, stream, rin, Wg1n, Wg2, gbuf);
    }
    hipLaunchKernelGGL(k_finalnll, dim3(128), dim3(256), 0, stream,
                       hbuf, gbuf, giE, gru_bhh, ow_bf, out_b, dec_tgt, word_tgt, nllG);
    hipLaunchKernelGGL(k_reduce, dim3(1), dim3(128), 0, stream, nllG, out);
}